// Round 4
// baseline (268.867 us; speedup 1.0000x reference)
//
#include <hip/hip_runtime.h>
#include <stdint.h>
#include <stddef.h>

// ---------------------------------------------------------------------------
// MultiHeadAttention (softmax intentionally skipped).  B=4 H=16 L=1024
// INPUT_DIM=1024 HID_DIM=64.
// out0 = energy = mask ? (Q K^T)/8 : -1e10   [B,H,L,L] f32  (256 MB)
// out1 = energy @ V  -> [B,L,H*64] f32                      (16 MB)
// Round 4: 3 kernels only.
//   k_wt:   wq/wk/wv f32 -> bf16 transposed Wt[n][k]
//   k_gemm: fused f32->bf16 A-staging (reg-staged, swizzled ds_write) +
//           gload_lds B. z==2 (V) writes TRANSPOSED Vt[bh*64+d][l] directly.
//   k_attn: block-coop LDS staging + swapped QK^T + coalesced B2 repass +
//           register mask prefetch (T14) with nontemporal loads.
// ---------------------------------------------------------------------------

typedef __attribute__((ext_vector_type(8))) short short8;
typedef __attribute__((ext_vector_type(4))) float f32x4;
typedef __attribute__((ext_vector_type(4))) int i32x4;
typedef __attribute__((ext_vector_type(2))) unsigned int u32x2;

#define MFMA16(a, b, c) __builtin_amdgcn_mfma_f32_16x16x32_bf16(a, b, c, 0, 0, 0)

using gptr_t = const __attribute__((address_space(1))) void*;
using lptr_t = __attribute__((address_space(3))) void*;

#define NEGV -10000000000.0f
#define NEGV_BF16 0xD015u  // f2bf(-1e10)

__device__ __forceinline__ unsigned short f2bf(float f) {
  uint32_t u = __builtin_bit_cast(uint32_t, f);
  u += 0x7FFFu + ((u >> 16) & 1u);  // RNE
  return (unsigned short)(u >> 16);
}

// ---- W[k][n] f32 -> Wt[n][k] bf16 (64x64 LDS tile transpose) ---------------
__global__ __launch_bounds__(256) void k_wt(
    const float* __restrict__ wq, const float* __restrict__ wk, const float* __restrict__ wv,
    unsigned short* __restrict__ tq, unsigned short* __restrict__ tk,
    unsigned short* __restrict__ tv) {
  const int z = blockIdx.z;
  const float* src = z == 0 ? wq : z == 1 ? wk : wv;
  unsigned short* dst = z == 0 ? tq : z == 1 ? tk : tv;
  __shared__ unsigned short t[64][65];
  const int n0 = blockIdx.x * 64, k0 = blockIdx.y * 64;
#pragma unroll
  for (int i = 0; i < 16; ++i) {
    const int idx = i * 256 + threadIdx.x;
    const int r = idx >> 6, c = idx & 63;
    t[r][c] = f2bf(src[(size_t)(k0 + r) * 1024 + n0 + c]);
  }
  __syncthreads();
#pragma unroll
  for (int i = 0; i < 16; ++i) {
    const int idx = i * 256 + threadIdx.x;
    const int r = idx >> 6, c = idx & 63;
    dst[(size_t)(n0 + r) * 1024 + k0 + c] = t[c][r];
  }
}

// ---- bf16 GEMM: C = X_f32 @ Wt^T + bias ------------------------------------
// A staged f32->bf16 in-kernel (reg-stage + swizzled ds_write_b128); B via
// global_load_lds with pre-swizzled source. z==2 writes transposed Vt.
__global__ __launch_bounds__(256) void k_gemm(
    const float* __restrict__ Xq, const float* __restrict__ Xk,
    const float* __restrict__ Xv,
    const unsigned short* __restrict__ Wq, const unsigned short* __restrict__ Wk,
    const unsigned short* __restrict__ Wv,
    const float* __restrict__ bq, const float* __restrict__ bk, const float* __restrict__ bv,
    unsigned short* __restrict__ Cq, unsigned short* __restrict__ Ck,
    unsigned short* __restrict__ Vt) {
  const int z = blockIdx.z;
  const float* X           = z == 0 ? Xq : z == 1 ? Xk : Xv;
  const unsigned short* Wt = z == 0 ? Wq : z == 1 ? Wk : Wv;
  const float* bias        = z == 0 ? bq : z == 1 ? bk : bv;

  __shared__ unsigned short Ads[128 * 64];
  __shared__ unsigned short Bds[128 * 64];

  const int tid = threadIdx.x;
  const int w = tid >> 6, l = tid & 63;
  const int lr = l & 15, g = l >> 4;
  const int m0 = blockIdx.y * 128, n0 = blockIdx.x * 128;
  const int wm = (w >> 1) * 64, wn = (w & 1) * 64;
  const int srow = tid >> 3, sslot = tid & 7;

  f32x4 acc[4][4];
#pragma unroll
  for (int mi = 0; mi < 4; ++mi)
#pragma unroll
    for (int ni = 0; ni < 4; ++ni) acc[mi][ni] = (f32x4){0.f, 0.f, 0.f, 0.f};

  for (int kt = 0; kt < 16; ++kt) {
    const int kb = kt * 64;
    // A: f32 -> bf16 reg-staged, swizzled LDS dest (c8 ^ (row&7))
#pragma unroll
    for (int i = 0; i < 4; ++i) {
      const int idx = i * 256 + tid;       // 0..1023
      const int row = idx >> 3, c8 = idx & 7;
      const float* ga = X + (size_t)(m0 + row) * 1024 + kb + c8 * 8;
      f32x4 a0 = *(const f32x4*)ga;
      f32x4 a1 = *(const f32x4*)(ga + 4);
      short8 pk;
      pk[0] = (short)f2bf(a0[0]); pk[1] = (short)f2bf(a0[1]);
      pk[2] = (short)f2bf(a0[2]); pk[3] = (short)f2bf(a0[3]);
      pk[4] = (short)f2bf(a1[0]); pk[5] = (short)f2bf(a1[1]);
      pk[6] = (short)f2bf(a1[2]); pk[7] = (short)f2bf(a1[3]);
      *(short8*)&Ads[row * 64 + ((c8 ^ (row & 7)) << 3)] = pk;
    }
    // B: bf16 gload_lds, pre-swizzled source
#pragma unroll
    for (int i = 0; i < 4; ++i) {
      const int row = i * 32 + srow;
      const int scol = ((sslot ^ (row & 7)) << 3);
      const unsigned short* gb = Wt + (size_t)(n0 + row) * 1024 + kb + scol;
      __builtin_amdgcn_global_load_lds((gptr_t)gb, (lptr_t)&Bds[(i * 32 + w * 8) * 64], 16, 0, 0);
    }
    __syncthreads();
    short8 afr[4][2], bfr[4][2];
#pragma unroll
    for (int t = 0; t < 4; ++t)
#pragma unroll
      for (int ks = 0; ks < 2; ++ks) {
        const int ra = wm + t * 16 + lr;
        afr[t][ks] = *(const short8*)&Ads[ra * 64 + (((ks * 4 + g) ^ (ra & 7)) << 3)];
        const int rb = wn + t * 16 + lr;
        bfr[t][ks] = *(const short8*)&Bds[rb * 64 + (((ks * 4 + g) ^ (rb & 7)) << 3)];
      }
#pragma unroll
    for (int ks = 0; ks < 2; ++ks)
#pragma unroll
      for (int mi = 0; mi < 4; ++mi)
#pragma unroll
        for (int ni = 0; ni < 4; ++ni)
          acc[mi][ni] = MFMA16(afr[mi][ks], bfr[ni][ks], acc[mi][ni]);
    __syncthreads();
  }

  if (z != 2) {
    unsigned short* C = z == 0 ? Cq : Ck;
#pragma unroll
    for (int mi = 0; mi < 4; ++mi)
#pragma unroll
      for (int ni = 0; ni < 4; ++ni) {
        const int n = n0 + wn + ni * 16 + lr;
        const float bs = bias[n];
        f32x4 a = acc[mi][ni];
#pragma unroll
        for (int r = 0; r < 4; ++r) {
          const int m = m0 + wm + mi * 16 + g * 4 + r;
          C[(size_t)m * 1024 + n] = f2bf(a[r] + bs);
        }
      }
  } else {
    // V: store transposed Vt[(b*16+h)*64+d][l], 4 consecutive l per lane
#pragma unroll
    for (int mi = 0; mi < 4; ++mi)
#pragma unroll
      for (int ni = 0; ni < 4; ++ni) {
        const int ng = n0 + wn + ni * 16 + lr;
        const int hh = ng >> 6, dd = ng & 63;
        const float bs = bias[ng];
        f32x4 a = acc[mi][ni];
        const int mg = m0 + wm + mi * 16 + g * 4;  // +r, same b, contiguous l
        const int bb = mg >> 10;
        const int ll = mg & 1023;
        u32x2 pk;
        pk[0] = (uint32_t)f2bf(a[0] + bs) | ((uint32_t)f2bf(a[1] + bs) << 16);
        pk[1] = (uint32_t)f2bf(a[2] + bs) | ((uint32_t)f2bf(a[3] + bs) << 16);
        *(u32x2*)&Vt[(size_t)((bb * 16 + hh) * 64 + dd) * 1024 + ll] = pk;
      }
  }
}

// ---- fused energy + mask + store + P@V, block-cooperative LDS --------------
// 512 thr = 8 waves x 16 q. grid (8, 64). LDS: K[128][64] + V[64][128] +
// P 8x[16][128] = 64 KB -> 2 blocks/CU. Mask prefetched into regs (T14).
__global__ __launch_bounds__(512, 4) void k_attn(
    const unsigned short* __restrict__ Qb, const unsigned short* __restrict__ Kb,
    const unsigned short* __restrict__ Vt, const int* __restrict__ mask,
    float* __restrict__ att, float* __restrict__ xout) {
  const int bh = blockIdx.y, b = bh >> 4, h = bh & 15;
  const int tid = threadIdx.x;
  const int w = tid >> 6, l = tid & 63;
  const int lr = l & 15, g = l >> 4;
  const int q0 = blockIdx.x * 128 + w * 16;  // wave's 16 q-rows

  __shared__ unsigned short Kl[128 * 64];      // [k][d], XOR-swizzled content
  __shared__ unsigned short Vl[64 * 128];      // [d][k], XOR-swizzled content
  __shared__ unsigned short Pl[8 * 16 * 128];  // per-wave [q][k], swizzled
  unsigned short* Pw = &Pl[w * 16 * 128];

  // Q fragment (B-operand): lane holds q-col = lr, d = ks*32 + g*8 ..+7
  short8 qf[2];
#pragma unroll
  for (int ks = 0; ks < 2; ++ks)
    qf[ks] = *(const short8*)&Qb[(size_t)(b * 1024 + q0 + lr) * 1024 +
                                 h * 64 + ks * 32 + g * 8];

  f32x4 xacc[4];
#pragma unroll
  for (int di = 0; di < 4; ++di) xacc[di] = (f32x4){0.f, 0.f, 0.f, 0.f};

  // prefetch kt=0 mask (B2 coalesced pattern: row=flat>>7, col=flat&127)
  i32x4 mnext[8];
#pragma unroll
  for (int p = 0; p < 8; ++p) {
    const int flat = p * 256 + l * 4;
    const int row = flat >> 7, col = flat & 127;
    mnext[p] = __builtin_nontemporal_load(
        (const i32x4*)&mask[(size_t)(b * 1024 + q0 + row) * 1024 + col]);
  }

  for (int kt = 0; kt < 8; ++kt) {
    const int kb = kt * 128;
    __syncthreads();  // all waves done reading K/V/P of previous tile
    // ---- stage K[128][64]: coalesced gload_lds, source pre-swizzled ----
#pragma unroll
    for (int i = 0; i < 2; ++i) {
      const int row = i * 64 + (tid >> 3);
      const int slot = tid & 7;
      const unsigned short* src = Kb + (size_t)(b * 1024 + kb + row) * 1024 +
                                  h * 64 + ((slot ^ (row & 7)) << 3);
      __builtin_amdgcn_global_load_lds((gptr_t)src, (lptr_t)&Kl[(i * 64 + w * 8) * 64], 16, 0, 0);
    }
    // ---- stage V[64][128] from Vt ----
#pragma unroll
    for (int i = 0; i < 2; ++i) {
      const int row = i * 32 + (tid >> 4);
      const int slot = tid & 15;
      const unsigned short* src = Vt + (size_t)(bh * 64 + row) * 1024 + kb +
                                  ((slot ^ (row & 7)) << 3);
      __builtin_amdgcn_global_load_lds((gptr_t)src, (lptr_t)&Vl[(i * 32 + w * 4) * 128], 16, 0, 0);
    }
    __syncthreads();  // drains vmcnt -> staged data visible

    // ---- QK^T: swapped mfma(K, Q); D col=q(lr), row=k(g*4+r) ----
    f32x4 s[8];
#pragma unroll
    for (int ni = 0; ni < 8; ++ni) {
      f32x4 a = (f32x4){0.f, 0.f, 0.f, 0.f};
#pragma unroll
      for (int ks = 0; ks < 2; ++ks) {
        const int row = ni * 16 + lr;
        short8 kf = *(const short8*)&Kl[row * 64 + (((ks * 4 + g) ^ (row & 7)) << 3)];
        a = MFMA16(kf, qf[ks], a);
      }
      s[ni] = a;
    }
    // ---- B1: scatter raw scaled bf16 P into per-wave LDS ----
#pragma unroll
    for (int ni = 0; ni < 8; ++ni) {
      u32x2 pk;
      pk[0] = (uint32_t)f2bf(s[ni][0] * 0.125f) | ((uint32_t)f2bf(s[ni][1] * 0.125f) << 16);
      pk[1] = (uint32_t)f2bf(s[ni][2] * 0.125f) | ((uint32_t)f2bf(s[ni][3] * 0.125f) << 16);
      const int colq = ni * 16 + g * 4;
      *(u32x2*)&Pw[lr * 128 + (colq ^ ((lr & 7) << 3))] = pk;
    }
    asm volatile("s_waitcnt lgkmcnt(0)" ::: "memory");
    __builtin_amdgcn_sched_barrier(0);
    // ---- B2: row-major coalesced repass: mask(reg), att store, P wb ----
#pragma unroll
    for (int p = 0; p < 8; ++p) {
      const int flat = p * 256 + l * 4;
      const int row = flat >> 7;   // 0..15 (q-local)
      const int col = flat & 127;  // k-local, multiple of 4
      const int eb = row * 128 + (col ^ ((row & 7) << 3));
      u32x2 pr = *(const u32x2*)&Pw[eb];
      const i32x4 mv = mnext[p];
      const uint32_t u0 = pr[0], u1 = pr[1];
      f32x4 e;
      e[0] = mv[0] ? __builtin_bit_cast(float, u0 << 16) : NEGV;
      e[1] = mv[1] ? __builtin_bit_cast(float, u0 & 0xFFFF0000u) : NEGV;
      e[2] = mv[2] ? __builtin_bit_cast(float, u1 << 16) : NEGV;
      e[3] = mv[3] ? __builtin_bit_cast(float, u1 & 0xFFFF0000u) : NEGV;
      __builtin_nontemporal_store(
          e, (f32x4*)&att[(size_t)(bh * 1024 + q0 + row) * 1024 + kb + col]);
      u32x2 wb;
      wb[0] = (mv[0] ? (u0 & 0xFFFFu) : NEGV_BF16) |
              ((mv[1] ? (u0 >> 16) : NEGV_BF16) << 16);
      wb[1] = (mv[2] ? (u1 & 0xFFFFu) : NEGV_BF16) |
              ((mv[3] ? (u1 >> 16) : NEGV_BF16) << 16);
      *(u32x2*)&Pw[eb] = wb;
    }
    // ---- prefetch next tile's mask (T14: consumed next iter's B2) ----
    const int kbn = (kt == 7) ? kb : kb + 128;
#pragma unroll
    for (int p = 0; p < 8; ++p) {
      const int flat = p * 256 + l * 4;
      const int row = flat >> 7, col = flat & 127;
      mnext[p] = __builtin_nontemporal_load(
          (const i32x4*)&mask[(size_t)(b * 1024 + q0 + row) * 1024 + kbn + col]);
    }
    asm volatile("s_waitcnt lgkmcnt(0)" ::: "memory");
    __builtin_amdgcn_sched_barrier(0);
    // ---- PV: x += P @ V ----
#pragma unroll
    for (int ks4 = 0; ks4 < 4; ++ks4) {
      const int colk = ks4 * 32 + g * 8;
      short8 pa = *(const short8*)&Pw[lr * 128 + (colk ^ ((lr & 7) << 3))];
#pragma unroll
      for (int di = 0; di < 4; ++di) {
        const int vr = di * 16 + lr;
        short8 vf = *(const short8*)&Vl[vr * 128 + (colk ^ ((vr & 7) << 3))];
        xacc[di] = MFMA16(pa, vf, xacc[di]);
      }
    }
    asm volatile("" ::: "memory");  // keep next-iter writes after these reads
  }

#pragma unroll
  for (int di = 0; di < 4; ++di) {
    f32x4 a = xacc[di];
#pragma unroll
    for (int r = 0; r < 4; ++r) {
      const int q = q0 + g * 4 + r;  // D row = q-local, col = d-local
      __builtin_nontemporal_store(
          a[r], &xout[(size_t)(b * 1024 + q) * 1024 + h * 64 + di * 16 + lr]);
    }
  }
}

extern "C" void kernel_launch(void* const* d_in, const int* in_sizes, int n_in,
                              void* d_out, int out_size, void* d_ws, size_t ws_size,
                              hipStream_t stream) {
  (void)in_sizes; (void)n_in; (void)out_size;
  const float* q   = (const float*)d_in[0];
  const float* k   = (const float*)d_in[1];
  const float* v   = (const float*)d_in[2];
  const int* mask  = (const int*)d_in[3];
  const float* wq  = (const float*)d_in[4];
  const float* bq  = (const float*)d_in[5];
  const float* wk  = (const float*)d_in[6];
  const float* bk  = (const float*)d_in[7];
  const float* wv  = (const float*)d_in[8];
  const float* bv  = (const float*)d_in[9];
  float* att = (float*)d_out;
  float* x   = att + (size_t)4 * 16 * 1024 * 1024;

  char* ws = (char*)d_ws;
  const size_t SZX = (size_t)4096 * 1024 * 2;  // 8 MB bf16 [4096][1024]
  const size_t SZW = (size_t)1024 * 1024 * 2;  // 2 MB bf16 [1024][1024]
  if (ws_size < 3 * SZX + 3 * SZW) return;     // 30 MB needed
  unsigned short* Wtq = (unsigned short*)(ws);
  unsigned short* Wtk = (unsigned short*)(ws + SZW);
  unsigned short* Wtv = (unsigned short*)(ws + 2 * SZW);
  unsigned short* Qb  = (unsigned short*)(ws + 3 * SZW);
  unsigned short* Kb  = (unsigned short*)(ws + 3 * SZW + SZX);
  unsigned short* Vt  = (unsigned short*)(ws + 3 * SZW + 2 * SZX);

  k_wt<<<dim3(16, 16, 3), 256, 0, stream>>>(wq, wk, wv, Wtq, Wtk, Wtv);
  k_gemm<<<dim3(8, 32, 3), 256, 0, stream>>>(q, k, v, Wtq, Wtk, Wtv,
                                             bq, bk, bv, Qb, Kb, Vt);
  k_attn<<<dim3(8, 64), 512, 0, stream>>>(Qb, Kb, Vt, mask, att, x);
}

// Round 5
// 175.120 us; speedup vs baseline: 1.5353x; 1.5353x over previous
//
#include <hip/hip_runtime.h>
#include <stdint.h>
#include <stddef.h>

// ---------------------------------------------------------------------------
// MultiHeadAttention (softmax intentionally skipped).  B=4 H=16 L=1024
// INPUT_DIM=1024 HID_DIM=64.
// out0 = energy = mask ? (Q K^T)/8 : -1e10   [B,H,L,L] f32  (256 MB)
// out1 = energy @ V  -> [B,L,H*64] f32                      (16 MB)
// Round 5:
//   k_maskpack: mask int32 (64 MB) -> bitmask (512 KB) via __ballot.
//   k_wt:   wq/wk/wv f32 -> bf16 transposed Wt[n][k]
//   k_gemm: fused f32->bf16 A-staging + gload_lds B; z==2 stores Vt directly.
//   k_attn: mask applied at B1 from L1-resident bitmask; att stored as
//           f32-expansion of masked bf16 P (err 7.8e5 << 2e8 threshold);
//           single lgkm drain per iteration. Plain (cached) loads only.
// ---------------------------------------------------------------------------

typedef __attribute__((ext_vector_type(8))) short short8;
typedef __attribute__((ext_vector_type(4))) float f32x4;
typedef __attribute__((ext_vector_type(4))) int i32x4;
typedef __attribute__((ext_vector_type(2))) unsigned int u32x2;

#define MFMA16(a, b, c) __builtin_amdgcn_mfma_f32_16x16x32_bf16(a, b, c, 0, 0, 0)

using gptr_t = const __attribute__((address_space(1))) void*;
using lptr_t = __attribute__((address_space(3))) void*;

#define NEGV -10000000000.0f

__device__ __forceinline__ unsigned short f2bf(float f) {
  uint32_t u = __builtin_bit_cast(uint32_t, f);
  u += 0x7FFFu + ((u >> 16) & 1u);  // RNE
  return (unsigned short)(u >> 16);
}

// ---- mask int32 -> bit-packed (64 ints -> one u64 via ballot) --------------
__global__ __launch_bounds__(256) void k_maskpack(const int* __restrict__ mask,
                                                  unsigned long long* __restrict__ mb) {
  const int wid = (blockIdx.x * 256 + threadIdx.x) >> 6;  // global wave id
  const int l = threadIdx.x & 63;
  // 4M ints / 64 = 65536 chunks; 512 blocks * 4 waves = 2048 waves -> 32/wave
#pragma unroll 4
  for (int i = 0; i < 32; ++i) {
    const size_t c = (size_t)wid * 32 + i;
    const int v = mask[c * 64 + l];
    const unsigned long long bits = __ballot(v != 0);
    if (l == 0) mb[c] = bits;
  }
}

// ---- W[k][n] f32 -> Wt[n][k] bf16 (64x64 LDS tile transpose) ---------------
__global__ __launch_bounds__(256) void k_wt(
    const float* __restrict__ wq, const float* __restrict__ wk, const float* __restrict__ wv,
    unsigned short* __restrict__ tq, unsigned short* __restrict__ tk,
    unsigned short* __restrict__ tv) {
  const int z = blockIdx.z;
  const float* src = z == 0 ? wq : z == 1 ? wk : wv;
  unsigned short* dst = z == 0 ? tq : z == 1 ? tk : tv;
  __shared__ unsigned short t[64][65];
  const int n0 = blockIdx.x * 64, k0 = blockIdx.y * 64;
#pragma unroll
  for (int i = 0; i < 16; ++i) {
    const int idx = i * 256 + threadIdx.x;
    const int r = idx >> 6, c = idx & 63;
    t[r][c] = f2bf(src[(size_t)(k0 + r) * 1024 + n0 + c]);
  }
  __syncthreads();
#pragma unroll
  for (int i = 0; i < 16; ++i) {
    const int idx = i * 256 + threadIdx.x;
    const int r = idx >> 6, c = idx & 63;
    dst[(size_t)(n0 + r) * 1024 + k0 + c] = t[c][r];
  }
}

// ---- bf16 GEMM: C = X_f32 @ Wt^T + bias ------------------------------------
__global__ __launch_bounds__(256) void k_gemm(
    const float* __restrict__ Xq, const float* __restrict__ Xk,
    const float* __restrict__ Xv,
    const unsigned short* __restrict__ Wq, const unsigned short* __restrict__ Wk,
    const unsigned short* __restrict__ Wv,
    const float* __restrict__ bq, const float* __restrict__ bk, const float* __restrict__ bv,
    unsigned short* __restrict__ Cq, unsigned short* __restrict__ Ck,
    unsigned short* __restrict__ Vt) {
  const int z = blockIdx.z;
  const float* X           = z == 0 ? Xq : z == 1 ? Xk : Xv;
  const unsigned short* Wt = z == 0 ? Wq : z == 1 ? Wk : Wv;
  const float* bias        = z == 0 ? bq : z == 1 ? bk : bv;

  __shared__ unsigned short Ads[128 * 64];
  __shared__ unsigned short Bds[128 * 64];

  const int tid = threadIdx.x;
  const int w = tid >> 6, l = tid & 63;
  const int lr = l & 15, g = l >> 4;
  const int m0 = blockIdx.y * 128, n0 = blockIdx.x * 128;
  const int wm = (w >> 1) * 64, wn = (w & 1) * 64;
  const int srow = tid >> 3, sslot = tid & 7;

  f32x4 acc[4][4];
#pragma unroll
  for (int mi = 0; mi < 4; ++mi)
#pragma unroll
    for (int ni = 0; ni < 4; ++ni) acc[mi][ni] = (f32x4){0.f, 0.f, 0.f, 0.f};

  for (int kt = 0; kt < 16; ++kt) {
    const int kb = kt * 64;
    // A: f32 -> bf16 reg-staged, swizzled LDS dest (c8 ^ (row&7))
#pragma unroll
    for (int i = 0; i < 4; ++i) {
      const int idx = i * 256 + tid;       // 0..1023
      const int row = idx >> 3, c8 = idx & 7;
      const float* ga = X + (size_t)(m0 + row) * 1024 + kb + c8 * 8;
      f32x4 a0 = *(const f32x4*)ga;
      f32x4 a1 = *(const f32x4*)(ga + 4);
      short8 pk;
      pk[0] = (short)f2bf(a0[0]); pk[1] = (short)f2bf(a0[1]);
      pk[2] = (short)f2bf(a0[2]); pk[3] = (short)f2bf(a0[3]);
      pk[4] = (short)f2bf(a1[0]); pk[5] = (short)f2bf(a1[1]);
      pk[6] = (short)f2bf(a1[2]); pk[7] = (short)f2bf(a1[3]);
      *(short8*)&Ads[row * 64 + ((c8 ^ (row & 7)) << 3)] = pk;
    }
    // B: bf16 gload_lds, pre-swizzled source
#pragma unroll
    for (int i = 0; i < 4; ++i) {
      const int row = i * 32 + srow;
      const int scol = ((sslot ^ (row & 7)) << 3);
      const unsigned short* gb = Wt + (size_t)(n0 + row) * 1024 + kb + scol;
      __builtin_amdgcn_global_load_lds((gptr_t)gb, (lptr_t)&Bds[(i * 32 + w * 8) * 64], 16, 0, 0);
    }
    __syncthreads();
    short8 afr[4][2], bfr[4][2];
#pragma unroll
    for (int t = 0; t < 4; ++t)
#pragma unroll
      for (int ks = 0; ks < 2; ++ks) {
        const int ra = wm + t * 16 + lr;
        afr[t][ks] = *(const short8*)&Ads[ra * 64 + (((ks * 4 + g) ^ (ra & 7)) << 3)];
        const int rb = wn + t * 16 + lr;
        bfr[t][ks] = *(const short8*)&Bds[rb * 64 + (((ks * 4 + g) ^ (rb & 7)) << 3)];
      }
#pragma unroll
    for (int ks = 0; ks < 2; ++ks)
#pragma unroll
      for (int mi = 0; mi < 4; ++mi)
#pragma unroll
        for (int ni = 0; ni < 4; ++ni)
          acc[mi][ni] = MFMA16(afr[mi][ks], bfr[ni][ks], acc[mi][ni]);
    __syncthreads();
  }

  if (z != 2) {
    unsigned short* C = z == 0 ? Cq : Ck;
#pragma unroll
    for (int mi = 0; mi < 4; ++mi)
#pragma unroll
      for (int ni = 0; ni < 4; ++ni) {
        const int n = n0 + wn + ni * 16 + lr;
        const float bs = bias[n];
        f32x4 a = acc[mi][ni];
#pragma unroll
        for (int r = 0; r < 4; ++r) {
          const int m = m0 + wm + mi * 16 + g * 4 + r;
          C[(size_t)m * 1024 + n] = f2bf(a[r] + bs);
        }
      }
  } else {
    // V: store transposed Vt[(b*16+h)*64+d][l], 4 consecutive l per lane
#pragma unroll
    for (int mi = 0; mi < 4; ++mi)
#pragma unroll
      for (int ni = 0; ni < 4; ++ni) {
        const int ng = n0 + wn + ni * 16 + lr;
        const int hh = ng >> 6, dd = ng & 63;
        const float bs = bias[ng];
        f32x4 a = acc[mi][ni];
        const int mg = m0 + wm + mi * 16 + g * 4;
        const int bb = mg >> 10;
        const int ll = mg & 1023;
        u32x2 pk;
        pk[0] = (uint32_t)f2bf(a[0] + bs) | ((uint32_t)f2bf(a[1] + bs) << 16);
        pk[1] = (uint32_t)f2bf(a[2] + bs) | ((uint32_t)f2bf(a[3] + bs) << 16);
        *(u32x2*)&Vt[(size_t)((bb * 16 + hh) * 64 + dd) * 1024 + ll] = pk;
      }
  }
}

// ---- fused energy + mask + store + P@V -------------------------------------
// 512 thr = 8 waves x 16 q. grid (8, 64). LDS 64 KB -> 2 blocks/CU.
// Mask from bit-packed mb (L1-resident per block). B1 writes MASKED bf16 P;
// B2 expands P -> f32 att (bf16 roundtrip err 7.8e5 << 2e8 threshold).
__global__ __launch_bounds__(512, 4) void k_attn(
    const unsigned short* __restrict__ Qb, const unsigned short* __restrict__ Kb,
    const unsigned short* __restrict__ Vt, const uint32_t* __restrict__ mb,
    float* __restrict__ att, float* __restrict__ xout) {
  const int bh = blockIdx.y, b = bh >> 4, h = bh & 15;
  const int tid = threadIdx.x;
  const int w = tid >> 6, l = tid & 63;
  const int lr = l & 15, g = l >> 4;
  const int q0 = blockIdx.x * 128 + w * 16;  // wave's 16 q-rows

  __shared__ unsigned short Kl[128 * 64];      // [k][d], XOR-swizzled content
  __shared__ unsigned short Vl[64 * 128];      // [d][k], XOR-swizzled content
  __shared__ unsigned short Pl[8 * 16 * 128];  // per-wave [q][k], swizzled
  unsigned short* Pw = &Pl[w * 16 * 128];

  // Q fragment (B-operand): lane holds q-col = lr, d = ks*32 + g*8 ..+7
  short8 qf[2];
#pragma unroll
  for (int ks = 0; ks < 2; ++ks)
    qf[ks] = *(const short8*)&Qb[(size_t)(b * 1024 + q0 + lr) * 1024 +
                                 h * 64 + ks * 32 + g * 8];

  f32x4 xacc[4];
#pragma unroll
  for (int di = 0; di < 4; ++di) xacc[di] = (f32x4){0.f, 0.f, 0.f, 0.f};

  for (int kt = 0; kt < 8; ++kt) {
    const int kb = kt * 128;
    __syncthreads();  // all waves done reading K/V of previous tile
    // ---- stage K[128][64]: coalesced gload_lds, source pre-swizzled ----
#pragma unroll
    for (int i = 0; i < 2; ++i) {
      const int row = i * 64 + (tid >> 3);
      const int slot = tid & 7;
      const unsigned short* src = Kb + (size_t)(b * 1024 + kb + row) * 1024 +
                                  h * 64 + ((slot ^ (row & 7)) << 3);
      __builtin_amdgcn_global_load_lds((gptr_t)src, (lptr_t)&Kl[(i * 64 + w * 8) * 64], 16, 0, 0);
    }
    // ---- stage V[64][128] from Vt ----
#pragma unroll
    for (int i = 0; i < 2; ++i) {
      const int row = i * 32 + (tid >> 4);
      const int slot = tid & 15;
      const unsigned short* src = Vt + (size_t)(bh * 64 + row) * 1024 + kb +
                                  ((slot ^ (row & 7)) << 3);
      __builtin_amdgcn_global_load_lds((gptr_t)src, (lptr_t)&Vl[(i * 32 + w * 4) * 128], 16, 0, 0);
    }
    // ---- this lane's 128-bit mask window (L1-hot: 16 KB/block) ----
    const i32x4 mw = *(const i32x4*)&mb[(size_t)(b * 1024 + q0 + lr) * 32 + kt * 4];
    __syncthreads();  // drains vmcnt -> staged data + mw ready

    // ---- QK^T: swapped mfma(K, Q); D col=q(lr), row=k(g*4+r) ----
    f32x4 s[8];
#pragma unroll
    for (int ni = 0; ni < 8; ++ni) {
      f32x4 a = (f32x4){0.f, 0.f, 0.f, 0.f};
#pragma unroll
      for (int ks = 0; ks < 2; ++ks) {
        const int row = ni * 16 + lr;
        short8 kf = *(const short8*)&Kl[row * 64 + (((ks * 4 + g) ^ (row & 7)) << 3)];
        a = MFMA16(kf, qf[ks], a);
      }
      s[ni] = a;
    }
    // ---- B1: mask + scale -> masked bf16 P scatter ----
#pragma unroll
    for (int ni = 0; ni < 8; ++ni) {
      const uint32_t wbits = (uint32_t)mw[ni >> 1];
      const int bit0 = (ni & 1) * 16 + g * 4;
      f32x4 e;
#pragma unroll
      for (int j = 0; j < 4; ++j)
        e[j] = ((wbits >> (bit0 + j)) & 1u) ? s[ni][j] * 0.125f : NEGV;
      u32x2 pk;
      pk[0] = (uint32_t)f2bf(e[0]) | ((uint32_t)f2bf(e[1]) << 16);
      pk[1] = (uint32_t)f2bf(e[2]) | ((uint32_t)f2bf(e[3]) << 16);
      const int colq = ni * 16 + g * 4;
      *(u32x2*)&Pw[lr * 128 + (colq ^ ((lr & 7) << 3))] = pk;
    }
    asm volatile("s_waitcnt lgkmcnt(0)" ::: "memory");
    __builtin_amdgcn_sched_barrier(0);
    // ---- B2: att = f32-expand of masked P (coalesced rows) ----
#pragma unroll
    for (int p = 0; p < 8; ++p) {
      const int flat = p * 256 + l * 4;
      const int row = flat >> 7;   // 0..15 (q-local)
      const int col = flat & 127;  // k-local, multiple of 4
      u32x2 pr = *(const u32x2*)&Pw[row * 128 + (col ^ ((row & 7) << 3))];
      const uint32_t u0 = pr[0], u1 = pr[1];
      f32x4 e;
      e[0] = __builtin_bit_cast(float, u0 << 16);
      e[1] = __builtin_bit_cast(float, u0 & 0xFFFF0000u);
      e[2] = __builtin_bit_cast(float, u1 << 16);
      e[3] = __builtin_bit_cast(float, u1 & 0xFFFF0000u);
      __builtin_nontemporal_store(
          e, (f32x4*)&att[(size_t)(bh * 1024 + q0 + row) * 1024 + kb + col]);
    }
    // ---- PV: x += P @ V  (reads only; no extra drain needed) ----
#pragma unroll
    for (int ks4 = 0; ks4 < 4; ++ks4) {
      const int colk = ks4 * 32 + g * 8;
      short8 pa = *(const short8*)&Pw[lr * 128 + (colk ^ ((lr & 7) << 3))];
#pragma unroll
      for (int di = 0; di < 4; ++di) {
        const int vr = di * 16 + lr;
        short8 vf = *(const short8*)&Vl[vr * 128 + (colk ^ ((vr & 7) << 3))];
        xacc[di] = MFMA16(pa, vf, xacc[di]);
      }
    }
    asm volatile("" ::: "memory");  // keep next-iter writes after these reads
  }

#pragma unroll
  for (int di = 0; di < 4; ++di) {
    f32x4 a = xacc[di];
#pragma unroll
    for (int r = 0; r < 4; ++r) {
      const int q = q0 + g * 4 + r;  // D row = q-local, col = d-local
      __builtin_nontemporal_store(
          a[r], &xout[(size_t)(b * 1024 + q) * 1024 + h * 64 + di * 16 + lr]);
    }
  }
}

extern "C" void kernel_launch(void* const* d_in, const int* in_sizes, int n_in,
                              void* d_out, int out_size, void* d_ws, size_t ws_size,
                              hipStream_t stream) {
  (void)in_sizes; (void)n_in; (void)out_size;
  const float* q   = (const float*)d_in[0];
  const float* k   = (const float*)d_in[1];
  const float* v   = (const float*)d_in[2];
  const int* mask  = (const int*)d_in[3];
  const float* wq  = (const float*)d_in[4];
  const float* bq  = (const float*)d_in[5];
  const float* wk  = (const float*)d_in[6];
  const float* bk  = (const float*)d_in[7];
  const float* wv  = (const float*)d_in[8];
  const float* bv  = (const float*)d_in[9];
  float* att = (float*)d_out;
  float* x   = att + (size_t)4 * 16 * 1024 * 1024;

  char* ws = (char*)d_ws;
  const size_t SZX = (size_t)4096 * 1024 * 2;   // 8 MB bf16 [4096][1024]
  const size_t SZW = (size_t)1024 * 1024 * 2;   // 2 MB bf16 [1024][1024]
  const size_t SZM = (size_t)4 * 1024 * 32 * 4; // 512 KB bitmask
  if (ws_size < 3 * SZX + 3 * SZW + SZM) return;
  unsigned short* Wtq = (unsigned short*)(ws);
  unsigned short* Wtk = (unsigned short*)(ws + SZW);
  unsigned short* Wtv = (unsigned short*)(ws + 2 * SZW);
  unsigned short* Qb  = (unsigned short*)(ws + 3 * SZW);
  unsigned short* Kb  = (unsigned short*)(ws + 3 * SZW + SZX);
  unsigned short* Vt  = (unsigned short*)(ws + 3 * SZW + 2 * SZX);
  unsigned long long* Mb = (unsigned long long*)(ws + 3 * SZW + 3 * SZX);

  k_maskpack<<<dim3(512), 256, 0, stream>>>(mask, Mb);
  k_wt<<<dim3(16, 16, 3), 256, 0, stream>>>(wq, wk, wv, Wtq, Wtk, Wtv);
  k_gemm<<<dim3(8, 32, 3), 256, 0, stream>>>(q, k, v, Wtq, Wtk, Wtv,
                                             bq, bk, bv, Qb, Kb, Vt);
  k_attn<<<dim3(8, 64), 512, 0, stream>>>(Qb, Kb, Vt, (const uint32_t*)Mb,
                                          att, x);
}

// Round 6
// 174.476 us; speedup vs baseline: 1.5410x; 1.0037x over previous
//
#include <hip/hip_runtime.h>
#include <stdint.h>
#include <stddef.h>

// ---------------------------------------------------------------------------
// MultiHeadAttention (softmax intentionally skipped).  B=4 H=16 L=1024
// out0 = energy = mask ? (Q K^T)/8 : -1e10   [B,H,L,L] f32  (256 MB)
// out1 = energy @ V  -> [B,L,H*64] f32                      (16 MB)
// Round 6: k_attn rebuilt as a counted-vmcnt pipeline (T3/T4):
//   - K/V LDS double-buffered (stage kt+1 while computing kt)
//   - raw s_barrier + s_waitcnt vmcnt(9): att stores FLOAT across barriers
//   - P halved to [16][64] per wave (LDS 80 KB -> 2 blocks/CU)
// k_maskpack/k_wt/k_gemm unchanged from round 5.
// ---------------------------------------------------------------------------

typedef __attribute__((ext_vector_type(8))) short short8;
typedef __attribute__((ext_vector_type(4))) float f32x4;
typedef __attribute__((ext_vector_type(4))) int i32x4;
typedef __attribute__((ext_vector_type(2))) unsigned int u32x2;

#define MFMA16(a, b, c) __builtin_amdgcn_mfma_f32_16x16x32_bf16(a, b, c, 0, 0, 0)

using gptr_t = const __attribute__((address_space(1))) void*;
using lptr_t = __attribute__((address_space(3))) void*;

#define NEGV -10000000000.0f

__device__ __forceinline__ unsigned short f2bf(float f) {
  uint32_t u = __builtin_bit_cast(uint32_t, f);
  u += 0x7FFFu + ((u >> 16) & 1u);  // RNE
  return (unsigned short)(u >> 16);
}

// ---- mask int32 -> bit-packed (64 ints -> one u64 via ballot) --------------
__global__ __launch_bounds__(256) void k_maskpack(const int* __restrict__ mask,
                                                  unsigned long long* __restrict__ mb) {
  const int wid = (blockIdx.x * 256 + threadIdx.x) >> 6;
  const int l = threadIdx.x & 63;
#pragma unroll 4
  for (int i = 0; i < 32; ++i) {
    const size_t c = (size_t)wid * 32 + i;
    const int v = mask[c * 64 + l];
    const unsigned long long bits = __ballot(v != 0);
    if (l == 0) mb[c] = bits;
  }
}

// ---- W[k][n] f32 -> Wt[n][k] bf16 (64x64 LDS tile transpose) ---------------
__global__ __launch_bounds__(256) void k_wt(
    const float* __restrict__ wq, const float* __restrict__ wk, const float* __restrict__ wv,
    unsigned short* __restrict__ tq, unsigned short* __restrict__ tk,
    unsigned short* __restrict__ tv) {
  const int z = blockIdx.z;
  const float* src = z == 0 ? wq : z == 1 ? wk : wv;
  unsigned short* dst = z == 0 ? tq : z == 1 ? tk : tv;
  __shared__ unsigned short t[64][65];
  const int n0 = blockIdx.x * 64, k0 = blockIdx.y * 64;
#pragma unroll
  for (int i = 0; i < 16; ++i) {
    const int idx = i * 256 + threadIdx.x;
    const int r = idx >> 6, c = idx & 63;
    t[r][c] = f2bf(src[(size_t)(k0 + r) * 1024 + n0 + c]);
  }
  __syncthreads();
#pragma unroll
  for (int i = 0; i < 16; ++i) {
    const int idx = i * 256 + threadIdx.x;
    const int r = idx >> 6, c = idx & 63;
    dst[(size_t)(n0 + r) * 1024 + k0 + c] = t[c][r];
  }
}

// ---- bf16 GEMM: C = X_f32 @ Wt^T + bias ------------------------------------
__global__ __launch_bounds__(256) void k_gemm(
    const float* __restrict__ Xq, const float* __restrict__ Xk,
    const float* __restrict__ Xv,
    const unsigned short* __restrict__ Wq, const unsigned short* __restrict__ Wk,
    const unsigned short* __restrict__ Wv,
    const float* __restrict__ bq, const float* __restrict__ bk, const float* __restrict__ bv,
    unsigned short* __restrict__ Cq, unsigned short* __restrict__ Ck,
    unsigned short* __restrict__ Vt) {
  const int z = blockIdx.z;
  const float* X           = z == 0 ? Xq : z == 1 ? Xk : Xv;
  const unsigned short* Wt = z == 0 ? Wq : z == 1 ? Wk : Wv;
  const float* bias        = z == 0 ? bq : z == 1 ? bk : bv;

  __shared__ unsigned short Ads[128 * 64];
  __shared__ unsigned short Bds[128 * 64];

  const int tid = threadIdx.x;
  const int w = tid >> 6, l = tid & 63;
  const int lr = l & 15, g = l >> 4;
  const int m0 = blockIdx.y * 128, n0 = blockIdx.x * 128;
  const int wm = (w >> 1) * 64, wn = (w & 1) * 64;
  const int srow = tid >> 3, sslot = tid & 7;

  f32x4 acc[4][4];
#pragma unroll
  for (int mi = 0; mi < 4; ++mi)
#pragma unroll
    for (int ni = 0; ni < 4; ++ni) acc[mi][ni] = (f32x4){0.f, 0.f, 0.f, 0.f};

  for (int kt = 0; kt < 16; ++kt) {
    const int kb = kt * 64;
#pragma unroll
    for (int i = 0; i < 4; ++i) {
      const int idx = i * 256 + tid;
      const int row = idx >> 3, c8 = idx & 7;
      const float* ga = X + (size_t)(m0 + row) * 1024 + kb + c8 * 8;
      f32x4 a0 = *(const f32x4*)ga;
      f32x4 a1 = *(const f32x4*)(ga + 4);
      short8 pk;
      pk[0] = (short)f2bf(a0[0]); pk[1] = (short)f2bf(a0[1]);
      pk[2] = (short)f2bf(a0[2]); pk[3] = (short)f2bf(a0[3]);
      pk[4] = (short)f2bf(a1[0]); pk[5] = (short)f2bf(a1[1]);
      pk[6] = (short)f2bf(a1[2]); pk[7] = (short)f2bf(a1[3]);
      *(short8*)&Ads[row * 64 + ((c8 ^ (row & 7)) << 3)] = pk;
    }
#pragma unroll
    for (int i = 0; i < 4; ++i) {
      const int row = i * 32 + srow;
      const int scol = ((sslot ^ (row & 7)) << 3);
      const unsigned short* gb = Wt + (size_t)(n0 + row) * 1024 + kb + scol;
      __builtin_amdgcn_global_load_lds((gptr_t)gb, (lptr_t)&Bds[(i * 32 + w * 8) * 64], 16, 0, 0);
    }
    __syncthreads();
    short8 afr[4][2], bfr[4][2];
#pragma unroll
    for (int t = 0; t < 4; ++t)
#pragma unroll
      for (int ks = 0; ks < 2; ++ks) {
        const int ra = wm + t * 16 + lr;
        afr[t][ks] = *(const short8*)&Ads[ra * 64 + (((ks * 4 + g) ^ (ra & 7)) << 3)];
        const int rb = wn + t * 16 + lr;
        bfr[t][ks] = *(const short8*)&Bds[rb * 64 + (((ks * 4 + g) ^ (rb & 7)) << 3)];
      }
#pragma unroll
    for (int ks = 0; ks < 2; ++ks)
#pragma unroll
      for (int mi = 0; mi < 4; ++mi)
#pragma unroll
        for (int ni = 0; ni < 4; ++ni)
          acc[mi][ni] = MFMA16(afr[mi][ks], bfr[ni][ks], acc[mi][ni]);
    __syncthreads();
  }

  if (z != 2) {
    unsigned short* C = z == 0 ? Cq : Ck;
#pragma unroll
    for (int mi = 0; mi < 4; ++mi)
#pragma unroll
      for (int ni = 0; ni < 4; ++ni) {
        const int n = n0 + wn + ni * 16 + lr;
        const float bs = bias[n];
        f32x4 a = acc[mi][ni];
#pragma unroll
        for (int r = 0; r < 4; ++r) {
          const int m = m0 + wm + mi * 16 + g * 4 + r;
          C[(size_t)m * 1024 + n] = f2bf(a[r] + bs);
        }
      }
  } else {
#pragma unroll
    for (int mi = 0; mi < 4; ++mi)
#pragma unroll
      for (int ni = 0; ni < 4; ++ni) {
        const int ng = n0 + wn + ni * 16 + lr;
        const int hh = ng >> 6, dd = ng & 63;
        const float bs = bias[ng];
        f32x4 a = acc[mi][ni];
        const int mg = m0 + wm + mi * 16 + g * 4;
        const int bb = mg >> 10;
        const int ll = mg & 1023;
        u32x2 pk;
        pk[0] = (uint32_t)f2bf(a[0] + bs) | ((uint32_t)f2bf(a[1] + bs) << 16);
        pk[1] = (uint32_t)f2bf(a[2] + bs) | ((uint32_t)f2bf(a[3] + bs) << 16);
        *(u32x2*)&Vt[(size_t)((bb * 16 + hh) * 64 + dd) * 1024 + ll] = pk;
      }
  }
}

// ---- fused energy + mask + store + P@V: counted-vmcnt pipeline -------------
// 512 thr = 8 waves x 16 q. grid (8, 64). LDS: K dbuf 32K + V dbuf 32K +
// P 8x[16][64] 16K = 80 KB -> 2 blocks/CU. One raw barrier per kt; att
// stores float across barriers (vmcnt(9) = 1 mask load + 8 stores newer
// than the 4 stage ops).
__global__ __launch_bounds__(512, 4) void k_attn(
    const unsigned short* __restrict__ Qb, const unsigned short* __restrict__ Kb,
    const unsigned short* __restrict__ Vt, const uint32_t* __restrict__ mb,
    float* __restrict__ att, float* __restrict__ xout) {
  const int bh = blockIdx.y, b = bh >> 4, h = bh & 15;
  const int tid = threadIdx.x;
  const int w = tid >> 6, l = tid & 63;
  const int lr = l & 15, g = l >> 4;
  const int q0 = blockIdx.x * 128 + w * 16;

  __shared__ unsigned short Kl[2][128 * 64];  // [k][d], XOR-swizzled content
  __shared__ unsigned short Vl[2][64 * 128];  // [d][k], XOR-swizzled content
  __shared__ unsigned short Pl[8][16 * 64];   // per-wave half-P, swizzled
  unsigned short* Pw = Pl[w];

#define STAGE_KV(t, bb)                                                          \
  do {                                                                           \
    const int kbs = (t) * 128;                                                   \
    _Pragma("unroll") for (int i = 0; i < 2; ++i) {                              \
      const int row = i * 64 + (tid >> 3);                                       \
      const int slot = tid & 7;                                                  \
      const unsigned short* src = Kb + (size_t)(b * 1024 + kbs + row) * 1024 +   \
                                  h * 64 + ((slot ^ (row & 7)) << 3);            \
      __builtin_amdgcn_global_load_lds((gptr_t)src,                              \
          (lptr_t)&Kl[bb][(i * 64 + w * 8) * 64], 16, 0, 0);                     \
    }                                                                            \
    _Pragma("unroll") for (int i = 0; i < 2; ++i) {                              \
      const int row = i * 32 + (tid >> 4);                                       \
      const int slot = tid & 15;                                                 \
      const unsigned short* src = Vt + (size_t)(bh * 64 + row) * 1024 + kbs +    \
                                  ((slot ^ (row & 7)) << 3);                     \
      __builtin_amdgcn_global_load_lds((gptr_t)src,                              \
          (lptr_t)&Vl[bb][(i * 32 + w * 4) * 128], 16, 0, 0);                    \
    }                                                                            \
  } while (0)

  // Q fragment (B-operand): lane holds q-col = lr, d = ks*32 + g*8 ..+7
  short8 qf[2];
#pragma unroll
  for (int ks = 0; ks < 2; ++ks)
    qf[ks] = *(const short8*)&Qb[(size_t)(b * 1024 + q0 + lr) * 1024 +
                                 h * 64 + ks * 32 + g * 8];

  f32x4 xacc[4];
#pragma unroll
  for (int di = 0; di < 4; ++di) xacc[di] = (f32x4){0.f, 0.f, 0.f, 0.f};

  const size_t mrow = (size_t)(b * 1024 + q0 + lr) * 32;

  // ---- prologue: stage tile 0, load mask window 0, full drain, barrier ----
  STAGE_KV(0, 0);
  i32x4 mwc = *(const i32x4*)&mb[mrow];
  asm volatile("s_waitcnt vmcnt(0)" ::: "memory");
  __builtin_amdgcn_s_barrier();
  __builtin_amdgcn_sched_barrier(0);

  for (int kt = 0; kt < 8; ++kt) {
    const int cur = kt & 1;
    const int kb = kt * 128;
    // stage next tile into the other buffer (4 vmem ops)
    if (kt < 7) STAGE_KV(kt + 1, cur ^ 1);
    // prefetch next mask window (1 vmem op; consumed next iter)
    i32x4 mwn = mwc;
    if (kt < 7) mwn = *(const i32x4*)&mb[mrow + (kt + 1) * 4];

    // ---- QK^T: swapped mfma(K, Q); D col=q(lr), row=k(g*4+r) ----
    f32x4 s[8];
#pragma unroll
    for (int ni = 0; ni < 8; ++ni) {
      f32x4 a = (f32x4){0.f, 0.f, 0.f, 0.f};
#pragma unroll
      for (int ks = 0; ks < 2; ++ks) {
        const int row = ni * 16 + lr;
        short8 kf = *(const short8*)&Kl[cur][row * 64 + (((ks * 4 + g) ^ (row & 7)) << 3)];
        a = MFMA16(kf, qf[ks], a);
      }
      s[ni] = a;
    }

    // ---- two k-halves of 64: B1 (mask+pack->P) / B2 (att store) / PV ----
#pragma unroll
    for (int hh = 0; hh < 2; ++hh) {
      // B1: masked bf16 P scatter into per-wave half-P
#pragma unroll
      for (int n2 = 0; n2 < 4; ++n2) {
        const int ni = hh * 4 + n2;
        const uint32_t wbits = (uint32_t)mwc[ni >> 1];
        const int bit0 = (ni & 1) * 16 + g * 4;
        f32x4 e;
#pragma unroll
        for (int j = 0; j < 4; ++j)
          e[j] = ((wbits >> (bit0 + j)) & 1u) ? s[ni][j] * 0.125f : NEGV;
        u32x2 pk;
        pk[0] = (uint32_t)f2bf(e[0]) | ((uint32_t)f2bf(e[1]) << 16);
        pk[1] = (uint32_t)f2bf(e[2]) | ((uint32_t)f2bf(e[3]) << 16);
        const int c16 = n2 * 2 + (g >> 1);  // 16B granule within 64-short row
        *(u32x2*)&Pw[lr * 64 + ((c16 ^ (lr & 7)) << 3) + (g & 1) * 4] = pk;
      }
      asm volatile("s_waitcnt lgkmcnt(0)" ::: "memory");
      __builtin_amdgcn_sched_barrier(0);
      // B2: coalesced expand P -> f32 att (rows of 64 cols)
#pragma unroll
      for (int p = 0; p < 4; ++p) {
        const int row = p * 4 + g;
        const int c16 = lr >> 1;
        u32x2 pr = *(const u32x2*)&Pw[row * 64 + ((c16 ^ (row & 7)) << 3) + (lr & 1) * 4];
        const uint32_t u0 = pr[0], u1 = pr[1];
        f32x4 e;
        e[0] = __builtin_bit_cast(float, u0 << 16);
        e[1] = __builtin_bit_cast(float, u0 & 0xFFFF0000u);
        e[2] = __builtin_bit_cast(float, u1 << 16);
        e[3] = __builtin_bit_cast(float, u1 & 0xFFFF0000u);
        __builtin_nontemporal_store(
            e, (f32x4*)&att[(size_t)(bh * 1024 + q0 + row) * 1024 + kb + hh * 64 + lr * 4]);
      }
      // PV: x += P_half @ V_half (reads only)
#pragma unroll
      for (int k2 = 0; k2 < 2; ++k2) {
        const int c16 = k2 * 4 + g;  // granule within half-P row
        short8 pa = *(const short8*)&Pw[lr * 64 + ((c16 ^ (lr & 7)) << 3)];
        const int colk = hh * 64 + k2 * 32 + g * 8;  // within full V row
#pragma unroll
        for (int di = 0; di < 4; ++di) {
          const int vr = di * 16 + lr;
          short8 vf = *(const short8*)&Vl[cur][vr * 128 + (colk ^ ((vr & 7) << 3))];
          xacc[di] = MFMA16(pa, vf, xacc[di]);
        }
      }
      asm volatile("s_waitcnt lgkmcnt(0)" ::: "memory");
      __builtin_amdgcn_sched_barrier(0);
    }

    mwc = mwn;
    if (kt < 7) {
      // 9 = 1 mask prefetch + 8 att stores newer than the 4 stage ops:
      // stage guaranteed complete, stores keep floating.
      asm volatile("s_waitcnt vmcnt(9)" ::: "memory");
      __builtin_amdgcn_s_barrier();
      __builtin_amdgcn_sched_barrier(0);
    }
  }
#undef STAGE_KV

#pragma unroll
  for (int di = 0; di < 4; ++di) {
    f32x4 a = xacc[di];
#pragma unroll
    for (int r = 0; r < 4; ++r) {
      const int q = q0 + g * 4 + r;
      __builtin_nontemporal_store(
          a[r], &xout[(size_t)(b * 1024 + q) * 1024 + h * 64 + di * 16 + lr]);
    }
  }
}

extern "C" void kernel_launch(void* const* d_in, const int* in_sizes, int n_in,
                              void* d_out, int out_size, void* d_ws, size_t ws_size,
                              hipStream_t stream) {
  (void)in_sizes; (void)n_in; (void)out_size;
  const float* q   = (const float*)d_in[0];
  const float* k   = (const float*)d_in[1];
  const float* v   = (const float*)d_in[2];
  const int* mask  = (const int*)d_in[3];
  const float* wq  = (const float*)d_in[4];
  const float* bq  = (const float*)d_in[5];
  const float* wk  = (const float*)d_in[6];
  const float* bk  = (const float*)d_in[7];
  const float* wv  = (const float*)d_in[8];
  const float* bv  = (const float*)d_in[9];
  float* att = (float*)d_out;
  float* x   = att + (size_t)4 * 16 * 1024 * 1024;

  char* ws = (char*)d_ws;
  const size_t SZX = (size_t)4096 * 1024 * 2;   // 8 MB bf16 [4096][1024]
  const size_t SZW = (size_t)1024 * 1024 * 2;   // 2 MB bf16 [1024][1024]
  const size_t SZM = (size_t)4 * 1024 * 32 * 4; // 512 KB bitmask
  if (ws_size < 3 * SZX + 3 * SZW + SZM) return;
  unsigned short* Wtq = (unsigned short*)(ws);
  unsigned short* Wtk = (unsigned short*)(ws + SZW);
  unsigned short* Wtv = (unsigned short*)(ws + 2 * SZW);
  unsigned short* Qb  = (unsigned short*)(ws + 3 * SZW);
  unsigned short* Kb  = (unsigned short*)(ws + 3 * SZW + SZX);
  unsigned short* Vt  = (unsigned short*)(ws + 3 * SZW + 2 * SZX);
  unsigned long long* Mb = (unsigned long long*)(ws + 3 * SZW + 3 * SZX);

  k_maskpack<<<dim3(512), 256, 0, stream>>>(mask, Mb);
  k_wt<<<dim3(16, 16, 3), 256, 0, stream>>>(wq, wk, wv, Wtq, Wtk, Wtv);
  k_gemm<<<dim3(8, 32, 3), 256, 0, stream>>>(q, k, v, Wtq, Wtk, Wtv,
                                             bq, bk, bv, Qb, Kb, Vt);
  k_attn<<<dim3(8, 64), 512, 0, stream>>>(Qb, Kb, Vt, (const uint32_t*)Mb,
                                          att, x);
}